// Round 7
// baseline (827.503 us; speedup 1.0000x reference)
//
#include <hip/hip_runtime.h>
#include <math.h>

#define BB 2
#define TT 2048
#define DD 2048
#define HH 16
#define KK 128

typedef _Float16 h4 __attribute__((ext_vector_type(4)));
typedef _Float16 v8h __attribute__((ext_vector_type(8)));
typedef float v4f __attribute__((ext_vector_type(4)));

// ---------------------------------------------------------------------------
// FALLBACK fp32 GEMM — used only if ws is too small for the f16 buffers.
// ---------------------------------------------------------------------------
__global__ __launch_bounds__(256) void gemm_nt3(const float* __restrict__ A,
                                                const float* __restrict__ W0,
                                                const float* __restrict__ W1,
                                                const float* __restrict__ W2,
                                                float* __restrict__ Cbase,
                                                int M, int N, int Kd) {
  __shared__ float As[8][128];
  __shared__ float Bs[8][128];
  const int z = blockIdx.z;
  const float* W = (z == 0) ? W0 : (z == 1) ? W1 : W2;
  float* C = Cbase + (size_t)z * M * N;
  const int tid = threadIdx.x;
  const int bm = blockIdx.y * 128;
  const int bn = blockIdx.x * 128;
  const int lrow = tid >> 1;
  const int lcol = (tid & 1) * 4;
  const int rm = (tid >> 4) * 8;
  const int rn = (tid & 15) * 8;
  const float* Ap = A + (size_t)(bm + lrow) * Kd + lcol;
  const float* Wp = W + (size_t)(bn + lrow) * Kd + lcol;
  float acc[8][8];
#pragma unroll
  for (int i = 0; i < 8; i++)
#pragma unroll
    for (int j = 0; j < 8; j++) acc[i][j] = 0.f;
  float4 av = *(const float4*)Ap;
  float4 wv = *(const float4*)Wp;
  for (int d0 = 0; d0 < Kd; d0 += 8) {
    __syncthreads();
    As[lcol + 0][lrow] = av.x; As[lcol + 1][lrow] = av.y;
    As[lcol + 2][lrow] = av.z; As[lcol + 3][lrow] = av.w;
    Bs[lcol + 0][lrow] = wv.x; Bs[lcol + 1][lrow] = wv.y;
    Bs[lcol + 2][lrow] = wv.z; Bs[lcol + 3][lrow] = wv.w;
    __syncthreads();
    if (d0 + 8 < Kd) {
      av = *(const float4*)(Ap + d0 + 8);
      wv = *(const float4*)(Wp + d0 + 8);
    }
#pragma unroll
    for (int kk = 0; kk < 8; kk++) {
      const float4 a0 = *(const float4*)&As[kk][rm];
      const float4 a1 = *(const float4*)&As[kk][rm + 4];
      const float4 b0 = *(const float4*)&Bs[kk][rn];
      const float4 b1 = *(const float4*)&Bs[kk][rn + 4];
      const float ar[8] = {a0.x, a0.y, a0.z, a0.w, a1.x, a1.y, a1.z, a1.w};
      const float br[8] = {b0.x, b0.y, b0.z, b0.w, b1.x, b1.y, b1.z, b1.w};
#pragma unroll
      for (int i = 0; i < 8; i++)
#pragma unroll
        for (int j = 0; j < 8; j++) acc[i][j] = fmaf(ar[i], br[j], acc[i][j]);
    }
  }
#pragma unroll
  for (int i = 0; i < 8; i++) {
    float* cp = C + (size_t)(bm + rm + i) * N + bn + rn;
    float4 c0 = {acc[i][0], acc[i][1], acc[i][2], acc[i][3]};
    float4 c1 = {acc[i][4], acc[i][5], acc[i][6], acc[i][7]};
    *(float4*)cp = c0;
    *(float4*)(cp + 4) = c1;
  }
}

// ---------------------------------------------------------------------------
// Convert: x -> xh + xl (f16 hi/lo split), Wq/Wk/Wv -> Wf (single f16).
// ---------------------------------------------------------------------------
__global__ __launch_bounds__(256) void convert_f16(
    const float* __restrict__ x, const float* __restrict__ Wq,
    const float* __restrict__ Wk, const float* __restrict__ Wv,
    _Float16* __restrict__ xh, _Float16* __restrict__ xl,
    _Float16* __restrict__ Wf) {
  const size_t N4X = (size_t)BB * TT * DD / 4;
  const size_t N4W = (size_t)(HH * KK) * DD / 4;
  const size_t i = (size_t)blockIdx.x * 256 + threadIdx.x;
  if (i < N4X) {
    const float4 v = ((const float4*)x)[i];
    h4 hi, lo;
    hi.x = (_Float16)v.x; hi.y = (_Float16)v.y;
    hi.z = (_Float16)v.z; hi.w = (_Float16)v.w;
    lo.x = (_Float16)(v.x - (float)hi.x);
    lo.y = (_Float16)(v.y - (float)hi.y);
    lo.z = (_Float16)(v.z - (float)hi.z);
    lo.w = (_Float16)(v.w - (float)hi.w);
    ((h4*)xh)[i] = hi;
    ((h4*)xl)[i] = lo;
  } else {
    const size_t j = i - N4X;
    const float* Ws = (j < N4W) ? Wq : (j < 2 * N4W) ? Wk : Wv;
    const size_t jj = (j < N4W) ? j : (j < 2 * N4W) ? (j - N4W) : (j - 2 * N4W);
    const float4 v = ((const float4*)Ws)[jj];
    h4 hi;
    hi.x = (_Float16)v.x; hi.y = (_Float16)v.y;
    hi.z = (_Float16)v.z; hi.w = (_Float16)v.w;
    ((h4*)Wf)[j] = hi;
  }
}

// ---------------------------------------------------------------------------
// MFMA GEMM: C[z] = xh*W[z]^T + xl*W[z]^T  (f16 in, fp32 out) — m97 structure
// ---------------------------------------------------------------------------
#define GLDS(gp, lp)                                              \
  __builtin_amdgcn_global_load_lds(                               \
      (const __attribute__((address_space(1))) void*)(gp),        \
      (__attribute__((address_space(3))) void*)(lp), 16, 0, 0)

__global__ __launch_bounds__(256) void gemm_mfma(
    const _Float16* __restrict__ xh, const _Float16* __restrict__ xl,
    const _Float16* __restrict__ Wf, float* __restrict__ Cbase) {
  __shared__ float4 lraw[1536];  // 24 KB = Ah | Al | Bs
  _Float16* Ah = (_Float16*)lraw;
  _Float16* Al = Ah + 4096;
  _Float16* Bs = Al + 4096;

  const int z = blockIdx.z;
  const _Float16* W = Wf + (size_t)z * DD * (HH * KK);
  float* C = Cbase + (size_t)z * (BB * TT) * (HH * KK);

  const int tid = threadIdx.x;
  const int w = tid >> 6;
  const int lane = tid & 63;
  const int bm = blockIdx.y * 128;
  const int bn = blockIdx.x * 128;
  const int wm = (w & 1) * 64;
  const int wn = (w >> 1) * 64;
  const int m16 = lane & 15;
  const int quad = lane >> 4;

  const _Float16* gAh = xh + (size_t)(bm + (tid >> 2)) * DD + (tid & 3) * 8;
  const _Float16* gAl = xl + (size_t)(bm + (tid >> 2)) * DD + (tid & 3) * 8;
  const _Float16* gB = W + (size_t)(bn + (tid >> 2)) * DD + (tid & 3) * 8;
  const int lb = w * 512;

  v4f acc[4][4];
#pragma unroll
  for (int i = 0; i < 4; i++)
#pragma unroll
    for (int j = 0; j < 4; j++) acc[i][j] = (v4f){0.f, 0.f, 0.f, 0.f};

  for (int d0 = 0; d0 < DD; d0 += 32) {
    GLDS(gAh + d0, Ah + lb);
    GLDS(gAh + d0 + 64 * DD, Ah + 2048 + lb);
    GLDS(gAl + d0, Al + lb);
    GLDS(gAl + d0 + 64 * DD, Al + 2048 + lb);
    GLDS(gB + d0, Bs + lb);
    GLDS(gB + d0 + 64 * DD, Bs + 2048 + lb);
    __syncthreads();
    v8h ah[4], al[4], bw[4];
#pragma unroll
    for (int i = 0; i < 4; i++) {
      ah[i] = *(const v8h*)&Ah[(wm + i * 16 + m16) * 32 + quad * 8];
      al[i] = *(const v8h*)&Al[(wm + i * 16 + m16) * 32 + quad * 8];
      bw[i] = *(const v8h*)&Bs[(wn + i * 16 + m16) * 32 + quad * 8];
    }
#pragma unroll
    for (int mi = 0; mi < 4; mi++)
#pragma unroll
      for (int ni = 0; ni < 4; ni++) {
        acc[mi][ni] = __builtin_amdgcn_mfma_f32_16x16x32_f16(ah[mi], bw[ni],
                                                             acc[mi][ni], 0, 0, 0);
        acc[mi][ni] = __builtin_amdgcn_mfma_f32_16x16x32_f16(al[mi], bw[ni],
                                                             acc[mi][ni], 0, 0, 0);
      }
    __syncthreads();
  }
#pragma unroll
  for (int mi = 0; mi < 4; mi++) {
#pragma unroll
    for (int r = 0; r < 4; r++) {
      float* cp =
          C + (size_t)(bm + wm + mi * 16 + quad * 4 + r) * (HH * KK) + bn + wn + m16;
#pragma unroll
      for (int ni = 0; ni < 4; ni++) cp[ni * 16] = acc[mi][ni][r];
    }
  }
}

// ---------------------------------------------------------------------------
// alpha/beta projections (unchanged)
// ---------------------------------------------------------------------------
__global__ __launch_bounds__(64) void ab_proj(const float* __restrict__ x,
                                              const float* __restrict__ Wa,
                                              const float* __restrict__ ba,
                                              const float* __restrict__ Wb,
                                              const float* __restrict__ bb,
                                              float* __restrict__ abq) {
  const int row = blockIdx.x;
  const int g = blockIdx.y;
  const int h0 = (g & 1) * 8;
  const bool isA = (g < 2);
  const float* W = isA ? Wa : Wb;
  const int lane = threadIdx.x;
  const float* xr = x + (size_t)row * DD;
  float acc[8];
#pragma unroll
  for (int j = 0; j < 8; j++) acc[j] = 0.f;
  for (int d = lane; d < DD; d += 64) {
    const float xv = xr[d];
#pragma unroll
    for (int j = 0; j < 8; j++)
      acc[j] = fmaf(xv, W[(size_t)(h0 + j) * DD + d], acc[j]);
  }
#pragma unroll
  for (int j = 0; j < 8; j++) {
#pragma unroll
    for (int off = 32; off > 0; off >>= 1) acc[j] += __shfl_xor(acc[j], off, 64);
  }
  if (lane == 0) {
    if (isA) {
#pragma unroll
      for (int j = 0; j < 8; j++) {
        const float z = acc[j] + ba[h0 + j];
        abq[((size_t)row * HH + h0 + j) * 4 + 0] = 1.0f / (1.0f + expf(-z));
      }
    } else {
#pragma unroll
      for (int j = 0; j < 8; j++) {
        const float z = acc[j] + bb[h0 + j];
        const float sp = (z > 20.f) ? z : log1pf(expf(z));
        abq[((size_t)row * HH + h0 + j) * 4 + 1] = sp * 0.08838834764831845f;
      }
    }
  }
}

// ---------------------------------------------------------------------------
// norm_pack: l2-normalize q,k; round to f16; write packed [k(128)|q(128)] f16
// per (b,t,h); kq-dot (from the ROUNDED values, self-consistent) -> abq slot 2.
// No f32 writeback — the scan reads only the packed f16 buffer.
// ---------------------------------------------------------------------------
__global__ __launch_bounds__(256) void norm_pack(const float* __restrict__ q,
                                                 const float* __restrict__ k,
                                                 _Float16* __restrict__ kq,
                                                 float* __restrict__ abq) {
  const int vec = blockIdx.x * 4 + (threadIdx.x >> 6);
  const int l = threadIdx.x & 63;
  const float* qp = q + (size_t)vec * 128;
  const float* kp = k + (size_t)vec * 128;
  float q0 = qp[l], q1 = qp[l + 64];
  float k0 = kp[l], k1 = kp[l + 64];
  float sq = q0 * q0 + q1 * q1;
  float sk = k0 * k0 + k1 * k1;
#pragma unroll
  for (int off = 32; off > 0; off >>= 1) {
    sq += __shfl_xor(sq, off, 64);
    sk += __shfl_xor(sk, off, 64);
  }
  const float iq = 1.0f / fmaxf(sqrtf(sq), 1e-12f);
  const float ik = 1.0f / fmaxf(sqrtf(sk), 1e-12f);
  const _Float16 hq0 = (_Float16)(q0 * iq), hq1 = (_Float16)(q1 * iq);
  const _Float16 hk0 = (_Float16)(k0 * ik), hk1 = (_Float16)(k1 * ik);
  _Float16* kv = kq + (size_t)vec * 256;
  kv[l] = hk0;
  kv[l + 64] = hk1;
  kv[l + 128] = hq0;
  kv[l + 192] = hq1;
  float pq = (float)hq0 * (float)hk0 + (float)hq1 * (float)hk1;
#pragma unroll
  for (int off = 32; off > 0; off >>= 1) pq += __shfl_xor(pq, off, 64);
  if (l == 0) abq[(size_t)vec * 4 + 2] = pq;
}

// ---------------------------------------------------------------------------
// Scan v5: 16-lane row-groups, 8 state f32/thread, all-DPP allreduce,
// no-copy depth-8 prefetch. NEW: k,q read as packed f16 (one stream, q at
// +256B) — cuts per-CU L1 return bytes ~2x (round-6 analysis: scan was
// L1-return-bound at ~21 KB/CU/step). (float)f16 in fmaf -> v_fma_mix_f32.
// ---------------------------------------------------------------------------
#define DPP_ADD(x, ctrl)                                                     \
  ((x) + __int_as_float(__builtin_amdgcn_update_dpp(                         \
             0, __float_as_int(x), (ctrl), 0xF, 0xF, true)))

#define SCAN_STEP(kc, qc, vc, ac, store_ptr)                                   \
  {                                                                            \
    float dkA = fmaf((float)kc[0], S0,                                         \
                     fmaf((float)kc[1], S1,                                    \
                          fmaf((float)kc[2], S2, (float)kc[3] * S3)));         \
    float dkB = fmaf((float)kc[4], S4,                                         \
                     fmaf((float)kc[5], S5,                                    \
                          fmaf((float)kc[6], S6, (float)kc[7] * S7)));         \
    float dqA = fmaf((float)qc[0], S0,                                         \
                     fmaf((float)qc[1], S1,                                    \
                          fmaf((float)qc[2], S2, (float)qc[3] * S3)));         \
    float dqB = fmaf((float)qc[4], S4,                                         \
                     fmaf((float)qc[5], S5,                                    \
                          fmaf((float)qc[6], S6, (float)qc[7] * S7)));         \
    float dk = dkA + dkB;                                                      \
    float dq = dqA + dqB;                                                      \
    dk = DPP_ADD(dk, 0xB1);  dq = DPP_ADD(dq, 0xB1);   /* width 2  */          \
    dk = DPP_ADD(dk, 0x4E);  dq = DPP_ADD(dq, 0x4E);   /* width 4  */          \
    dk = DPP_ADD(dk, 0x141); dq = DPP_ADD(dq, 0x141);  /* width 8  */          \
    dk = DPP_ADD(dk, 0x140); dq = DPP_ADD(dq, 0x140);  /* width 16 */          \
    const float u = ac.y * (vc - ac.x * dk);                                   \
    const float oo = fmaf(ac.x, dq, u * ac.z);                                 \
    S0 = fmaf(ac.x, S0, u * (float)kc[0]);                                     \
    S1 = fmaf(ac.x, S1, u * (float)kc[1]);                                     \
    S2 = fmaf(ac.x, S2, u * (float)kc[2]);                                     \
    S3 = fmaf(ac.x, S3, u * (float)kc[3]);                                     \
    S4 = fmaf(ac.x, S4, u * (float)kc[4]);                                     \
    S5 = fmaf(ac.x, S5, u * (float)kc[5]);                                     \
    S6 = fmaf(ac.x, S6, u * (float)kc[6]);                                     \
    S7 = fmaf(ac.x, S7, u * (float)kc[7]);                                     \
    if (g == 0) *(store_ptr) = oo;                                             \
  }

#define PD 8  // prefetch depth
#define KQSTRIDE (HH * 256)  // f16 elems per time step

__global__ __launch_bounds__(256) void scan_kernel(
    const _Float16* __restrict__ kq, const float* __restrict__ v,
    const float* __restrict__ abq, float* __restrict__ o) {
  const int bid = blockIdx.x;  // = s*32 + bh (V-splits of a bh share an XCD)
  const int bh = bid & 31;
  const int s = bid >> 5;  // 0..7
  const int h = bh & 15;
  const int b = bh >> 4;
  const int tid = threadIdx.x;
  const int w = tid >> 6;
  const int lane = tid & 63;
  const int rg = lane >> 4;  // 0..3 row within wave
  const int g = lane & 15;   // 0..15 k-group (8 elems)
  const int vrow = s * 16 + w * 4 + rg;

  const _Float16* kqb = kq + ((size_t)b * TT * HH + h) * 256 + g * 8;
  const float* vb = v + (size_t)b * TT * 2048 + (size_t)h * KK + vrow;
  const float* ab = abq + ((size_t)b * TT * HH + h) * 4;
  float* ob = o + (size_t)b * TT * 2048 + (size_t)h * KK + vrow;

  float S0 = 0.f, S1 = 0.f, S2 = 0.f, S3 = 0.f;
  float S4 = 0.f, S5 = 0.f, S6 = 0.f, S7 = 0.f;

  v8h kf[PD], qf[PD];
  float4 af[PD];
  float vf[PD];
#pragma unroll
  for (int d = 0; d < PD; d++) {
    kf[d] = *(const v8h*)(kqb + d * KQSTRIDE);
    qf[d] = *(const v8h*)(kqb + d * KQSTRIDE + 128);
    vf[d] = vb[d * 2048];
    af[d] = *(const float4*)(ab + d * 64);
  }

  int off = 0;   // uniform f16-elem offset into kq, +KQSTRIDE per step
  int offv = 0;  // uniform f32 offset for v/o, +2048 per step
  int aoff = 0;  // uniform abq offset, +64 per step
  for (int t0 = 0; t0 < TT - PD; t0 += PD) {
#pragma unroll
    for (int j = 0; j < PD; j++) {
      // consume slot j (no copy — the loads below overwrite it afterwards)
      SCAN_STEP(kf[j], qf[j], vf[j], af[j], ob + offv + j * 2048);
      // reload slot j with step t0+j+PD
      kf[j] = *(const v8h*)(kqb + off + (j + PD) * KQSTRIDE);
      qf[j] = *(const v8h*)(kqb + off + (j + PD) * KQSTRIDE + 128);
      vf[j] = vb[offv + (j + PD) * 2048];
      af[j] = *(const float4*)(ab + aoff + (j + PD) * 64);
      __builtin_amdgcn_sched_barrier(0);  // loads may not sink past here
    }
    off += PD * KQSTRIDE;
    offv += PD * 2048;
    aoff += PD * 64;
  }
  // final PD steps: consume only
#pragma unroll
  for (int j = 0; j < PD; j++) {
    SCAN_STEP(kf[j], qf[j], vf[j], af[j], ob + offv + j * 2048);
  }
}

// ---------------------------------------------------------------------------
extern "C" void kernel_launch(void* const* d_in, const int* in_sizes, int n_in,
                              void* d_out, int out_size, void* d_ws,
                              size_t ws_size, hipStream_t stream) {
  const float* x = (const float*)d_in[0];
  const float* Wq = (const float*)d_in[1];
  const float* Wk = (const float*)d_in[2];
  const float* Wv = (const float*)d_in[3];
  const float* Wa = (const float*)d_in[4];
  const float* ba = (const float*)d_in[5];
  const float* Wb = (const float*)d_in[6];
  const float* bb = (const float*)d_in[7];
  float* out = (float*)d_out;
  float* ws = (float*)d_ws;

  const size_t PROJ = (size_t)BB * TT * HH * KK;  // 8,388,608
  const size_t NABQ = (size_t)BB * TT * HH * 4;
  float* qw = ws;
  float* kw = ws + PROJ;
  float* vw = ws + 2 * PROJ;
  float* abq = ws + 3 * PROJ;
  _Float16* xh = (_Float16*)(abq + NABQ);
  _Float16* xl = xh + (size_t)BB * TT * DD;
  _Float16* Wf = xl + (size_t)BB * TT * DD;
  const size_t NEED = (3 * PROJ + NABQ) * 4 +
                      ((size_t)BB * TT * DD * 2 + 3 * (size_t)(HH * KK) * DD) * 2;

  const int M = BB * TT;  // 4096
  const int N = HH * KK;  // 2048
  _Float16* kqf16;
  if (ws_size >= NEED) {
    const int cgrid = (int)(((size_t)BB * TT * DD / 4 + 3 * (size_t)N * DD / 4) / 256);
    convert_f16<<<cgrid, 256, 0, stream>>>(x, Wq, Wk, Wv, xh, xl, Wf);
    gemm_mfma<<<dim3(N / 128, M / 128, 3), 256, 0, stream>>>(xh, xl, Wf, qw);
    // xh/xl (33.6 MB) are dead after gemm_mfma; reuse for the packed kq (33.5 MB)
    kqf16 = xh;
  } else {
    gemm_nt3<<<dim3(N / 128, M / 128, 3), 256, 0, stream>>>(x, Wq, Wk, Wv, qw,
                                                            M, N, DD);
    kqf16 = (_Float16*)(abq + NABQ);
  }
  ab_proj<<<dim3(M, 4), 64, 0, stream>>>(x, Wa, ba, Wb, bb, abq);
  norm_pack<<<(BB * TT * HH) / 4, 256, 0, stream>>>(qw, kw, kqf16, abq);
  scan_kernel<<<BB * HH * 8, 256, 0, stream>>>(kqf16, vw, abq, out);
}

// Round 8
// 814.814 us; speedup vs baseline: 1.0156x; 1.0156x over previous
//
#include <hip/hip_runtime.h>
#include <math.h>

#define BB 2
#define TT 2048
#define DD 2048
#define HH 16
#define KK 128

typedef _Float16 h4 __attribute__((ext_vector_type(4)));
typedef _Float16 v8h __attribute__((ext_vector_type(8)));
typedef float v4f __attribute__((ext_vector_type(4)));
typedef float v2f __attribute__((ext_vector_type(2)));

// ---------------------------------------------------------------------------
// FALLBACK fp32 GEMM — used only if ws is too small for the f16 buffers.
// ---------------------------------------------------------------------------
__global__ __launch_bounds__(256) void gemm_nt3(const float* __restrict__ A,
                                                const float* __restrict__ W0,
                                                const float* __restrict__ W1,
                                                const float* __restrict__ W2,
                                                float* __restrict__ Cbase,
                                                int M, int N, int Kd) {
  __shared__ float As[8][128];
  __shared__ float Bs[8][128];
  const int z = blockIdx.z;
  const float* W = (z == 0) ? W0 : (z == 1) ? W1 : W2;
  float* C = Cbase + (size_t)z * M * N;
  const int tid = threadIdx.x;
  const int bm = blockIdx.y * 128;
  const int bn = blockIdx.x * 128;
  const int lrow = tid >> 1;
  const int lcol = (tid & 1) * 4;
  const int rm = (tid >> 4) * 8;
  const int rn = (tid & 15) * 8;
  const float* Ap = A + (size_t)(bm + lrow) * Kd + lcol;
  const float* Wp = W + (size_t)(bn + lrow) * Kd + lcol;
  float acc[8][8];
#pragma unroll
  for (int i = 0; i < 8; i++)
#pragma unroll
    for (int j = 0; j < 8; j++) acc[i][j] = 0.f;
  float4 av = *(const float4*)Ap;
  float4 wv = *(const float4*)Wp;
  for (int d0 = 0; d0 < Kd; d0 += 8) {
    __syncthreads();
    As[lcol + 0][lrow] = av.x; As[lcol + 1][lrow] = av.y;
    As[lcol + 2][lrow] = av.z; As[lcol + 3][lrow] = av.w;
    Bs[lcol + 0][lrow] = wv.x; Bs[lcol + 1][lrow] = wv.y;
    Bs[lcol + 2][lrow] = wv.z; Bs[lcol + 3][lrow] = wv.w;
    __syncthreads();
    if (d0 + 8 < Kd) {
      av = *(const float4*)(Ap + d0 + 8);
      wv = *(const float4*)(Wp + d0 + 8);
    }
#pragma unroll
    for (int kk = 0; kk < 8; kk++) {
      const float4 a0 = *(const float4*)&As[kk][rm];
      const float4 a1 = *(const float4*)&As[kk][rm + 4];
      const float4 b0 = *(const float4*)&Bs[kk][rn];
      const float4 b1 = *(const float4*)&Bs[kk][rn + 4];
      const float ar[8] = {a0.x, a0.y, a0.z, a0.w, a1.x, a1.y, a1.z, a1.w};
      const float br[8] = {b0.x, b0.y, b0.z, b0.w, b1.x, b1.y, b1.z, b1.w};
#pragma unroll
      for (int i = 0; i < 8; i++)
#pragma unroll
        for (int j = 0; j < 8; j++) acc[i][j] = fmaf(ar[i], br[j], acc[i][j]);
    }
  }
#pragma unroll
  for (int i = 0; i < 8; i++) {
    float* cp = C + (size_t)(bm + rm + i) * N + bn + rn;
    float4 c0 = {acc[i][0], acc[i][1], acc[i][2], acc[i][3]};
    float4 c1 = {acc[i][4], acc[i][5], acc[i][6], acc[i][7]};
    *(float4*)cp = c0;
    *(float4*)(cp + 4) = c1;
  }
}

// ---------------------------------------------------------------------------
// Convert: x -> xh + xl (f16 hi/lo split), Wq/Wk/Wv -> Wf (single f16).
// ---------------------------------------------------------------------------
__global__ __launch_bounds__(256) void convert_f16(
    const float* __restrict__ x, const float* __restrict__ Wq,
    const float* __restrict__ Wk, const float* __restrict__ Wv,
    _Float16* __restrict__ xh, _Float16* __restrict__ xl,
    _Float16* __restrict__ Wf) {
  const size_t N4X = (size_t)BB * TT * DD / 4;
  const size_t N4W = (size_t)(HH * KK) * DD / 4;
  const size_t i = (size_t)blockIdx.x * 256 + threadIdx.x;
  if (i < N4X) {
    const float4 v = ((const float4*)x)[i];
    h4 hi, lo;
    hi.x = (_Float16)v.x; hi.y = (_Float16)v.y;
    hi.z = (_Float16)v.z; hi.w = (_Float16)v.w;
    lo.x = (_Float16)(v.x - (float)hi.x);
    lo.y = (_Float16)(v.y - (float)hi.y);
    lo.z = (_Float16)(v.z - (float)hi.z);
    lo.w = (_Float16)(v.w - (float)hi.w);
    ((h4*)xh)[i] = hi;
    ((h4*)xl)[i] = lo;
  } else {
    const size_t j = i - N4X;
    const float* Ws = (j < N4W) ? Wq : (j < 2 * N4W) ? Wk : Wv;
    const size_t jj = (j < N4W) ? j : (j < 2 * N4W) ? (j - N4W) : (j - 2 * N4W);
    const float4 v = ((const float4*)Ws)[jj];
    h4 hi;
    hi.x = (_Float16)v.x; hi.y = (_Float16)v.y;
    hi.z = (_Float16)v.z; hi.w = (_Float16)v.w;
    ((h4*)Wf)[j] = hi;
  }
}

// ---------------------------------------------------------------------------
// MFMA GEMM: C[z] = xh*W[z]^T + xl*W[z]^T  (f16 in, fp32 out) — m97 structure
// ---------------------------------------------------------------------------
#define GLDS(gp, lp)                                              \
  __builtin_amdgcn_global_load_lds(                               \
      (const __attribute__((address_space(1))) void*)(gp),        \
      (__attribute__((address_space(3))) void*)(lp), 16, 0, 0)
#define GLDS4(gp, lp)                                             \
  __builtin_amdgcn_global_load_lds(                               \
      (const __attribute__((address_space(1))) void*)(gp),        \
      (__attribute__((address_space(3))) void*)(lp), 4, 0, 0)

__global__ __launch_bounds__(256) void gemm_mfma(
    const _Float16* __restrict__ xh, const _Float16* __restrict__ xl,
    const _Float16* __restrict__ Wf, float* __restrict__ Cbase) {
  __shared__ float4 lraw[1536];  // 24 KB = Ah | Al | Bs
  _Float16* Ah = (_Float16*)lraw;
  _Float16* Al = Ah + 4096;
  _Float16* Bs = Al + 4096;

  const int z = blockIdx.z;
  const _Float16* W = Wf + (size_t)z * DD * (HH * KK);
  float* C = Cbase + (size_t)z * (BB * TT) * (HH * KK);

  const int tid = threadIdx.x;
  const int w = tid >> 6;
  const int lane = tid & 63;
  const int bm = blockIdx.y * 128;
  const int bn = blockIdx.x * 128;
  const int wm = (w & 1) * 64;
  const int wn = (w >> 1) * 64;
  const int m16 = lane & 15;
  const int quad = lane >> 4;

  const _Float16* gAh = xh + (size_t)(bm + (tid >> 2)) * DD + (tid & 3) * 8;
  const _Float16* gAl = xl + (size_t)(bm + (tid >> 2)) * DD + (tid & 3) * 8;
  const _Float16* gB = W + (size_t)(bn + (tid >> 2)) * DD + (tid & 3) * 8;
  const int lb = w * 512;

  v4f acc[4][4];
#pragma unroll
  for (int i = 0; i < 4; i++)
#pragma unroll
    for (int j = 0; j < 4; j++) acc[i][j] = (v4f){0.f, 0.f, 0.f, 0.f};

  for (int d0 = 0; d0 < DD; d0 += 32) {
    GLDS(gAh + d0, Ah + lb);
    GLDS(gAh + d0 + 64 * DD, Ah + 2048 + lb);
    GLDS(gAl + d0, Al + lb);
    GLDS(gAl + d0 + 64 * DD, Al + 2048 + lb);
    GLDS(gB + d0, Bs + lb);
    GLDS(gB + d0 + 64 * DD, Bs + 2048 + lb);
    __syncthreads();
    v8h ah[4], al[4], bw[4];
#pragma unroll
    for (int i = 0; i < 4; i++) {
      ah[i] = *(const v8h*)&Ah[(wm + i * 16 + m16) * 32 + quad * 8];
      al[i] = *(const v8h*)&Al[(wm + i * 16 + m16) * 32 + quad * 8];
      bw[i] = *(const v8h*)&Bs[(wn + i * 16 + m16) * 32 + quad * 8];
    }
#pragma unroll
    for (int mi = 0; mi < 4; mi++)
#pragma unroll
      for (int ni = 0; ni < 4; ni++) {
        acc[mi][ni] = __builtin_amdgcn_mfma_f32_16x16x32_f16(ah[mi], bw[ni],
                                                             acc[mi][ni], 0, 0, 0);
        acc[mi][ni] = __builtin_amdgcn_mfma_f32_16x16x32_f16(al[mi], bw[ni],
                                                             acc[mi][ni], 0, 0, 0);
      }
    __syncthreads();
  }
#pragma unroll
  for (int mi = 0; mi < 4; mi++) {
#pragma unroll
    for (int r = 0; r < 4; r++) {
      float* cp =
          C + (size_t)(bm + wm + mi * 16 + quad * 4 + r) * (HH * KK) + bn + wn + m16;
#pragma unroll
      for (int ni = 0; ni < 4; ni++) cp[ni * 16] = acc[mi][ni][r];
    }
  }
}

// ---------------------------------------------------------------------------
// alpha/beta projections (unchanged)
// ---------------------------------------------------------------------------
__global__ __launch_bounds__(64) void ab_proj(const float* __restrict__ x,
                                              const float* __restrict__ Wa,
                                              const float* __restrict__ ba,
                                              const float* __restrict__ Wb,
                                              const float* __restrict__ bb,
                                              float* __restrict__ abq) {
  const int row = blockIdx.x;
  const int g = blockIdx.y;
  const int h0 = (g & 1) * 8;
  const bool isA = (g < 2);
  const float* W = isA ? Wa : Wb;
  const int lane = threadIdx.x;
  const float* xr = x + (size_t)row * DD;
  float acc[8];
#pragma unroll
  for (int j = 0; j < 8; j++) acc[j] = 0.f;
  for (int d = lane; d < DD; d += 64) {
    const float xv = xr[d];
#pragma unroll
    for (int j = 0; j < 8; j++)
      acc[j] = fmaf(xv, W[(size_t)(h0 + j) * DD + d], acc[j]);
  }
#pragma unroll
  for (int j = 0; j < 8; j++) {
#pragma unroll
    for (int off = 32; off > 0; off >>= 1) acc[j] += __shfl_xor(acc[j], off, 64);
  }
  if (lane == 0) {
    if (isA) {
#pragma unroll
      for (int j = 0; j < 8; j++) {
        const float z = acc[j] + ba[h0 + j];
        abq[((size_t)row * HH + h0 + j) * 4 + 0] = 1.0f / (1.0f + expf(-z));
      }
    } else {
#pragma unroll
      for (int j = 0; j < 8; j++) {
        const float z = acc[j] + bb[h0 + j];
        const float sp = (z > 20.f) ? z : log1pf(expf(z));
        abq[((size_t)row * HH + h0 + j) * 4 + 1] = sp * 0.08838834764831845f;
      }
    }
  }
}

// ---------------------------------------------------------------------------
// l2-normalize q,k in place (f32); kq = dot(qn,kn) -> abq slot 2.
// ---------------------------------------------------------------------------
__global__ __launch_bounds__(256) void norm_qk(float* __restrict__ q,
                                               float* __restrict__ k,
                                               float* __restrict__ abq) {
  const int vec = blockIdx.x * 4 + (threadIdx.x >> 6);
  const int l = threadIdx.x & 63;
  float* qp = q + (size_t)vec * 128;
  float* kp = k + (size_t)vec * 128;
  float q0 = qp[l], q1 = qp[l + 64];
  float k0 = kp[l], k1 = kp[l + 64];
  float sq = q0 * q0 + q1 * q1;
  float sk = k0 * k0 + k1 * k1;
#pragma unroll
  for (int off = 32; off > 0; off >>= 1) {
    sq += __shfl_xor(sq, off, 64);
    sk += __shfl_xor(sk, off, 64);
  }
  const float iq = 1.0f / fmaxf(sqrtf(sq), 1e-12f);
  const float ik = 1.0f / fmaxf(sqrtf(sk), 1e-12f);
  q0 *= iq; q1 *= iq; k0 *= ik; k1 *= ik;
  qp[l] = q0; qp[l + 64] = q1;
  kp[l] = k0; kp[l + 64] = k1;
  float pq = q0 * k0 + q1 * k1;
#pragma unroll
  for (int off = 32; off > 0; off >>= 1) pq += __shfl_xor(pq, off, 64);
  if (l == 0) abq[(size_t)vec * 4 + 2] = pq;
}

// ---------------------------------------------------------------------------
// Scan v6: LDS-ring pipelined scan.
// Why: rounds 3-7 proved the compiler sinks register prefetch of globals
// (VGPR 56/84 vs the 104/168 live slots require) — exposing ~250 cyc/step of
// load latency. global_load_lds has no SSA value, so it CANNOT be sunk; the
// HW queue carries the latency and ds_read (~120 cyc) is covered by a 2-step
// register pipeline.
//   Ring: 4 slots x 8 steps. Per step 1 KB: k(512B)|q(512B) staged by ONE
//   width-16 instr (lanes<32 source kw, lanes>=32 source qw). v: width-4,
//   4 steps/instr. ab: width-16, 8 lanes. 3 staging instrs/wave/window.
//   Sync: raw s_barrier + manual s_waitcnt vmcnt(8): per wave/window exactly
//   8 o-stores + 3 stagings enter the vmcnt FIFO; the newest 8 outstanding
//   are the previous window's stores, so vmcnt(8) guarantees windows W and
//   W+1 are staged (in-order retirement, m135) without waiting on stores.
//   Compute: 16-lane row groups, all-DPP reduce, float2 pk-fma math.
// ---------------------------------------------------------------------------
#define DPP_ADD(x, ctrl)                                                     \
  ((x) + __int_as_float(__builtin_amdgcn_update_dpp(                         \
             0, __float_as_int(x), (ctrl), 0xF, 0xF, true)))

#define WSTEPS 8
#define NWIN (TT / WSTEPS)  // 256
#define VB 32768            // v ring base (after 4*8*1024 kq ring)
#define ABB 34816           // ab ring base (after 4*8*64 v ring)
#define V2F(p) (*(const v2f*)&(p))

struct Slot {
  float4 kA, kB, qA, qB, ab;
  float vv;
};

__global__ __launch_bounds__(256) void scan_kernel(const float* __restrict__ q,
                                                   const float* __restrict__ k,
                                                   const float* __restrict__ v,
                                                   const float* __restrict__ abq,
                                                   float* __restrict__ o) {
  __shared__ __attribute__((aligned(16))) char lds[35328];
  const int bid = blockIdx.x;  // = s*32 + bh (V-splits of a bh share an XCD)
  const int bh = bid & 31;
  const int s = bid >> 5;  // 0..7
  const int h = bh & 15;
  const int b = bh >> 4;
  const int tid = threadIdx.x;
  const int w = tid >> 6;
  const int lane = tid & 63;
  const int rg = lane >> 4;       // 0..3 row within wave
  const int g = lane & 15;        // 0..15 k-group (8 floats)
  const int rowloc = w * 4 + rg;  // 0..15 row within block
  const int vrow = s * 16 + rowloc;

  float* ob = o + (size_t)b * TT * 2048 + (size_t)h * KK + vrow;

  // ---- staging (3 global_load_lds per wave per window) ----
  auto stage = [&](int Wst) {
    const int t0 = Wst * WSTEPS;
    const int slot = Wst & 3;
#pragma unroll
    for (int i = 0; i < 3; i++) {
      const int id = w * 3 + i;
      if (id < 8) {  // kq step t0+id: 1 KB, lanes<32 from k, >=32 from q
        const int t = t0 + id;
        const size_t vecbase = ((size_t)(b * TT + t) * HH + h) * 128;
        const float* src = (lane < 32) ? (k + vecbase + lane * 4)
                                       : (q + vecbase + (size_t)(lane - 32) * 4);
        GLDS(src, lds + slot * 8192 + id * 1024);
      } else if (id < 10) {  // v: 4 steps x 16 rows, width 4
        const int t4 = t0 + (id - 8) * 4;
        const float* src = v + (size_t)(b * TT + t4 + (lane >> 4)) * 2048 +
                           h * 128 + s * 16 + (lane & 15);
        GLDS4(src, lds + VB + slot * 512 + (id - 8) * 256);
      } else {  // ab: 8 steps x 16 B, lanes<8 (id 10 & 11 duplicate, harmless)
        if (lane < 8) {
          const float* src =
              abq + ((size_t)(b * TT + t0 + lane) * HH + h) * 4;
          GLDS(src, lds + ABB + slot * 128);
        }
      }
    }
  };

#define LOAD_SLOT(S_, t_)                                                   \
  {                                                                         \
    const int _m = (t_) & 31;                                               \
    S_.kA = *(const float4*)(lds + _m * 1024 + g * 32);                     \
    S_.kB = *(const float4*)(lds + _m * 1024 + g * 32 + 16);                \
    S_.qA = *(const float4*)(lds + _m * 1024 + 512 + g * 32);               \
    S_.qB = *(const float4*)(lds + _m * 1024 + 512 + g * 32 + 16);          \
    S_.vv = *(const float*)(lds + VB + _m * 64 + rowloc * 4);               \
    S_.ab = *(const float4*)(lds + ABB + _m * 16);                          \
  }

#define STEP(S_, t_)                                                        \
  {                                                                         \
    const v2f k0 = V2F(S_.kA.x), k1 = V2F(S_.kA.z);                         \
    const v2f k2 = V2F(S_.kB.x), k3 = V2F(S_.kB.z);                         \
    const v2f q0 = V2F(S_.qA.x), q1 = V2F(S_.qA.z);                         \
    const v2f q2 = V2F(S_.qB.x), q3 = V2F(S_.qB.z);                         \
    v2f aK = __builtin_elementwise_fma(                                     \
        k0, Sv0,                                                            \
        __builtin_elementwise_fma(                                          \
            k1, Sv1, __builtin_elementwise_fma(k2, Sv2, k3 * Sv3)));        \
    v2f aQ = __builtin_elementwise_fma(                                     \
        q0, Sv0,                                                            \
        __builtin_elementwise_fma(                                          \
            q1, Sv1, __builtin_elementwise_fma(q2, Sv2, q3 * Sv3)));        \
    float dk = aK.x + aK.y, dq = aQ.x + aQ.y;                               \
    dk = DPP_ADD(dk, 0xB1);  dq = DPP_ADD(dq, 0xB1);                        \
    dk = DPP_ADD(dk, 0x4E);  dq = DPP_ADD(dq, 0x4E);                        \
    dk = DPP_ADD(dk, 0x141); dq = DPP_ADD(dq, 0x141);                       \
    dk = DPP_ADD(dk, 0x140); dq = DPP_ADD(dq, 0x140);                       \
    const float a_ = S_.ab.x, b_ = S_.ab.y, kqd = S_.ab.z;                  \
    const float u = b_ * (S_.vv - a_ * dk);                                 \
    const float oo = fmaf(a_, dq, u * kqd);                                 \
    const v2f a2 = {a_, a_}, u2 = {u, u};                                   \
    Sv0 = __builtin_elementwise_fma(a2, Sv0, u2 * k0);                      \
    Sv1 = __builtin_elementwise_fma(a2, Sv1, u2 * k1);                      \
    Sv2 = __builtin_elementwise_fma(a2, Sv2, u2 * k2);                      \
    Sv3 = __builtin_elementwise_fma(a2, Sv3, u2 * k3);                      \
    if (g == 0) ob[(size_t)(t_) * 2048] = oo;                               \
  }

  // prologue: stage windows 0,1; drain; barrier; prime register pipeline
  stage(0);
  stage(1);
  __builtin_amdgcn_s_waitcnt(0x0F70);  // vmcnt(0)
  __builtin_amdgcn_s_barrier();

  Slot slA, slB;
  LOAD_SLOT(slA, 0);
  LOAD_SLOT(slB, 1);

  v2f Sv0 = {0.f, 0.f}, Sv1 = {0.f, 0.f}, Sv2 = {0.f, 0.f}, Sv3 = {0.f, 0.f};

  for (int W = 0; W < NWIN; W++) {
    if (W >= 1) {
      __builtin_amdgcn_s_waitcnt(0x0F78);  // vmcnt(8): windows W,W+1 staged
      __builtin_amdgcn_s_barrier();
    }
    if (W + 2 < NWIN) stage(W + 2);
    const int t0 = W * WSTEPS;
#pragma unroll
    for (int j = 0; j < WSTEPS; j += 2) {
      const int t = t0 + j;
      STEP(slA, t);
      {
        const int tp = (t + 2 < TT) ? t + 2 : t;  // clamp; reread harmless
        LOAD_SLOT(slA, tp);
      }
      __builtin_amdgcn_sched_barrier(0);
      STEP(slB, t + 1);
      {
        const int tp = (t + 3 < TT) ? t + 3 : t;
        LOAD_SLOT(slB, tp);
      }
      __builtin_amdgcn_sched_barrier(0);
    }
  }
}

// ---------------------------------------------------------------------------
extern "C" void kernel_launch(void* const* d_in, const int* in_sizes, int n_in,
                              void* d_out, int out_size, void* d_ws,
                              size_t ws_size, hipStream_t stream) {
  const float* x = (const float*)d_in[0];
  const float* Wq = (const float*)d_in[1];
  const float* Wk = (const float*)d_in[2];
  const float* Wv = (const float*)d_in[3];
  const float* Wa = (const float*)d_in[4];
  const float* ba = (const float*)d_in[5];
  const float* Wb = (const float*)d_in[6];
  const float* bb = (const float*)d_in[7];
  float* out = (float*)d_out;
  float* ws = (float*)d_ws;

  const size_t PROJ = (size_t)BB * TT * HH * KK;  // 8,388,608
  const size_t NABQ = (size_t)BB * TT * HH * 4;
  float* qw = ws;
  float* kw = ws + PROJ;
  float* vw = ws + 2 * PROJ;
  float* abq = ws + 3 * PROJ;
  _Float16* xh = (_Float16*)(abq + NABQ);
  _Float16* xl = xh + (size_t)BB * TT * DD;
  _Float16* Wf = xl + (size_t)BB * TT * DD;
  const size_t NEED = (3 * PROJ + NABQ) * 4 +
                      ((size_t)BB * TT * DD * 2 + 3 * (size_t)(HH * KK) * DD) * 2;

  const int M = BB * TT;  // 4096
  const int N = HH * KK;  // 2048
  if (ws_size >= NEED) {
    const int cgrid = (int)(((size_t)BB * TT * DD / 4 + 3 * (size_t)N * DD / 4) / 256);
    convert_f16<<<cgrid, 256, 0, stream>>>(x, Wq, Wk, Wv, xh, xl, Wf);
    gemm_mfma<<<dim3(N / 128, M / 128, 3), 256, 0, stream>>>(xh, xl, Wf, qw);
  } else {
    gemm_nt3<<<dim3(N / 128, M / 128, 3), 256, 0, stream>>>(x, Wq, Wk, Wv, qw,
                                                            M, N, DD);
  }
  ab_proj<<<dim3(M, 4), 64, 0, stream>>>(x, Wa, ba, Wb, bb, abq);
  norm_qk<<<(BB * TT * HH) / 4, 256, 0, stream>>>(qw, kw, abq);
  scan_kernel<<<BB * HH * 8, 256, 0, stream>>>(qw, kw, vw, abq, out);
}